// Round 5
// baseline (7236.993 us; speedup 1.0000x reference)
//
#include <hip/hip_runtime.h>
#include <hip/hip_bf16.h>

#define NFEAT 256
#define NHID  128
#define NCLS  10
#define CONV_TIME 30
#define NSLICE 8          // feature slices == XCD count
#define SFEAT  16         // NHID / NSLICE; 64B rows

// ---------------------------------------------------------------- degree histogram
// NOTE: harness stages integer inputs as int32 (NOT int64) — read as int.
__global__ void deg_kernel(const int* __restrict__ ei, int* __restrict__ cnt, int E) {
    int e = blockIdx.x * blockDim.x + threadIdx.x;
    if (e < E) {
        int d = ei[(size_t)E + e];   // edge_index[1][e]
        atomicAdd(&cnt[d], 1);
    }
}

// ---------------------------------------------------------------- dinv = 1/sqrt(deg+1)
__global__ void dinv_kernel(const int* __restrict__ cnt, float* __restrict__ dinv, int n) {
    int i = blockIdx.x * blockDim.x + threadIdx.x;
    if (i < n) {
        float deg = (float)(cnt[i] + 1);   // +1 self loop; always >= 1
        dinv[i] = 1.0f / sqrtf(deg);
    }
}

// ---------------------------------------------------------------- exclusive scan (single block)
__global__ void scan_kernel(const int* __restrict__ cnt, int* __restrict__ offs,
                            int* __restrict__ pos, int n) {
    __shared__ int lds[256];
    int tid = threadIdx.x;
    int per = (n + 255) >> 8;
    int beg = tid * per;
    int end = min(beg + per, n);
    int sum = 0;
    for (int i = beg; i < end; ++i) sum += cnt[i];
    lds[tid] = sum;
    __syncthreads();
    if (tid == 0) {
        int acc = 0;
        for (int i = 0; i < 256; ++i) { int t = lds[i]; lds[i] = acc; acc += t; }
    }
    __syncthreads();
    int run = lds[tid];
    for (int i = beg; i < end; ++i) { offs[i] = run; pos[i] = run; run += cnt[i]; }
    if (tid == 255) offs[n] = run;
}

// ---------------------------------------------------------------- scatter edges into CSR (by dst)
// Payload is ONLY the src id (4B); normalization folded into the recurrence.
__global__ void scatter_kernel(const int* __restrict__ ei, int* __restrict__ pos,
                               int* __restrict__ esrc, int E) {
    int e = blockIdx.x * blockDim.x + threadIdx.x;
    if (e < E) {
        int s = ei[e];
        int d = ei[(size_t)E + e];
        int p = atomicAdd(&pos[d], 1);
        esrc[p] = s;
    }
}

// ---------------------------------------------------------------- zero the dummy row (row n) in both g buffers
__global__ void init_dummy_kernel(float* __restrict__ hA, float* __restrict__ hB,
                                  int n, int np1) {
    int t = threadIdx.x;
    if (t < NSLICE * SFEAT) {
        int sl = t >> 4, f = t & 15;
        size_t idx = (size_t)sl * np1 * SFEAT + (size_t)n * SFEAT + f;
        hA[idx] = 0.0f;
        hB[idx] = 0.0f;
    }
}

// ---------------------------------------------------------------- g0 = dinv * (x @ W1 + b1), sliced layout
__global__ __launch_bounds__(256) void gemm1_kernel(const float* __restrict__ x,
                                                    const float* __restrict__ W1,
                                                    const float* __restrict__ b1,
                                                    const float* __restrict__ dinv,
                                                    float* __restrict__ g, int M, int np1) {
    __shared__ float As[64][20];
    __shared__ float Bs[16][128];
    int tid = threadIdx.x;
    int m0  = blockIdx.x * 64;
    int tx  = tid & 15;
    int ty  = tid >> 4;
    int ar  = tid >> 2, aq = tid & 3;
    int br  = tid >> 4, bc = tid & 15;

    float acc[4][8];
#pragma unroll
    for (int i = 0; i < 4; ++i)
#pragma unroll
        for (int j = 0; j < 8; ++j) acc[i][j] = 0.0f;

    for (int kb = 0; kb < NFEAT; kb += 16) {
        float4 av = make_float4(0.f, 0.f, 0.f, 0.f);
        int arow = m0 + ar;
        if (arow < M) av = *(const float4*)(x + (size_t)arow * NFEAT + kb + aq * 4);
        *(float4*)&As[ar][aq * 4] = av;
        *(float4*)&Bs[br][bc * 8]     = *(const float4*)(W1 + (size_t)(kb + br) * NHID + bc * 8);
        *(float4*)&Bs[br][bc * 8 + 4] = *(const float4*)(W1 + (size_t)(kb + br) * NHID + bc * 8 + 4);
        __syncthreads();
#pragma unroll
        for (int k = 0; k < 16; ++k) {
            float a0 = As[ty * 4 + 0][k];
            float a1 = As[ty * 4 + 1][k];
            float a2 = As[ty * 4 + 2][k];
            float a3 = As[ty * 4 + 3][k];
            float4 b0 = *(float4*)&Bs[k][tx * 8];
            float4 b1v = *(float4*)&Bs[k][tx * 8 + 4];
            float bv[8] = {b0.x, b0.y, b0.z, b0.w, b1v.x, b1v.y, b1v.z, b1v.w};
            float avv[4] = {a0, a1, a2, a3};
#pragma unroll
            for (int i = 0; i < 4; ++i)
#pragma unroll
                for (int j = 0; j < 8; ++j)
                    acc[i][j] = fmaf(avv[i], bv[j], acc[i][j]);
        }
        __syncthreads();
    }
    int col0 = tx * 8;
    int sl   = col0 >> 4;
    int c0   = col0 & 15;
#pragma unroll
    for (int i = 0; i < 4; ++i) {
        int row = m0 + ty * 4 + i;
        if (row < M) {
            float dv = dinv[row];
            float* dst = g + (size_t)sl * np1 * SFEAT + (size_t)row * SFEAT + c0;
#pragma unroll
            for (int j = 0; j < 8; ++j)
                dst[j] = dv * (acc[i][j] + b1[col0 + j]);
        }
    }
}

// ---------------------------------------------------------------- one propagation hop (sliced, node-parallel slots)
// blockIdx & 7 = feature slice (round-robin onto 8 XCDs -> each XCD gathers only
// from its own 3.2MB slice, L2-resident; proven by R4's FETCH 361->41MB).
// Wave = 16 node-slots x 4 lanes; each lane holds float4 (slot's 16 feats).
// Each slot walks ITS OWN node's edge list -> no cross-slot reduction, no shfl
// per edge. One gather instr = 16 rows x 64B. Slot-degree divergence handled by
// clamped index + cndmask src -> dummy row n (zeroed, stays L1-hot).
// esrc is read nontemporal so its 6.4MB stream doesn't evict the slice from L2.
__global__ __launch_bounds__(256) void hop_kernel(const float* __restrict__ gin,
                                                  float* __restrict__ gout,
                                                  const int* __restrict__ offs,
                                                  const int* __restrict__ esrc,
                                                  const float* __restrict__ dinv,
                                                  int n, int np1, int last) {
    int bid  = blockIdx.x;
    int sl   = bid & (NSLICE - 1);
    int grp  = (bid >> 3) * 4 + (threadIdx.x >> 6);   // 16-node group
    if (grp * 16 >= n) return;
    int lane = threadIdx.x & 63;
    int slot = lane >> 2;          // 0..15
    int fl   = lane & 3;           // float4 within the 16-feat slice
    int node = grp * 16 + slot;
    bool valid = node < n;
    int nodeC = valid ? node : n;
    const float4* __restrict__ gs4 = (const float4*)(gin + (size_t)sl * np1 * SFEAT);
    float4*       __restrict__ go4 = (float4*)(gout + (size_t)sl * np1 * SFEAT);

    int beg = 0, deg = 0;
    if (valid) { beg = offs[node]; deg = offs[node + 1] - beg; }
    int dmax = deg;
    dmax = max(dmax, __shfl_xor(dmax, 4, 64));
    dmax = max(dmax, __shfl_xor(dmax, 8, 64));
    dmax = max(dmax, __shfl_xor(dmax, 16, 64));
    dmax = max(dmax, __shfl_xor(dmax, 32, 64));

    float4 acc = make_float4(0.f, 0.f, 0.f, 0.f);
    int degm1 = (deg > 0) ? (deg - 1) : 0;
#pragma unroll 4
    for (int i = 0; i < dmax; ++i) {
        int a   = beg + min(i, degm1);                      // always in-bounds
        int src = __builtin_nontemporal_load(&esrc[a]);
        src     = (i < deg) ? src : n;                      // dummy row = zeros
        float4 v = gs4[(size_t)src * 4 + fl];
        acc.x += v.x; acc.y += v.y; acc.z += v.z; acc.w += v.w;
    }
    float4 sf = gs4[(size_t)nodeC * 4 + fl];
    acc.x += sf.x; acc.y += sf.y; acc.z += sf.z; acc.w += sf.w;
    float dv = valid ? dinv[node] : 1.0f;
    float sc = last ? dv : dv * dv;
    acc.x *= sc; acc.y *= sc; acc.z *= sc; acc.w *= sc;
    if (valid) go4[(size_t)node * 4 + fl] = acc;
}

// ---------------------------------------------------------------- out = relu(h) @ Wc + bc (sliced h)
__global__ __launch_bounds__(256) void cls_kernel(const float* __restrict__ h,
                                                  const float* __restrict__ Wc,
                                                  const float* __restrict__ bc,
                                                  float* __restrict__ out, int n, int np1) {
    __shared__ float wc[NHID * NCLS];
    __shared__ float bcs[NCLS];
    int tid = threadIdx.x;
    for (int i = tid; i < NHID * NCLS; i += 256) wc[i] = Wc[i];
    if (tid < NCLS) bcs[tid] = bc[tid];
    __syncthreads();
    int i = blockIdx.x * 256 + tid;
    if (i >= n) return;
    float acc[NCLS];
#pragma unroll
    for (int c = 0; c < NCLS; ++c) acc[c] = bcs[c];
#pragma unroll
    for (int s = 0; s < NSLICE; ++s) {
        const float4* hr = (const float4*)(h + ((size_t)s * np1 + i) * SFEAT);
#pragma unroll
        for (int q = 0; q < 4; ++q) {
            float4 v = hr[q];
            float vs[4] = {fmaxf(v.x, 0.f), fmaxf(v.y, 0.f), fmaxf(v.z, 0.f), fmaxf(v.w, 0.f)};
#pragma unroll
            for (int j = 0; j < 4; ++j)
#pragma unroll
                for (int c = 0; c < NCLS; ++c)
                    acc[c] = fmaf(vs[j], wc[(s * SFEAT + q * 4 + j) * NCLS + c], acc[c]);
        }
    }
#pragma unroll
    for (int c = 0; c < NCLS; ++c) out[(size_t)i * NCLS + c] = acc[c];
}

// ----------------------------------------------------------------
static inline size_t align256(size_t x) { return (x + 255) & ~(size_t)255; }

extern "C" void kernel_launch(void* const* d_in, const int* in_sizes, int n_in,
                              void* d_out, int out_size, void* d_ws, size_t ws_size,
                              hipStream_t stream) {
    const float* x   = (const float*)d_in[0];
    const int*   ei  = (const int*)d_in[1];     // int64 in reference -> staged as int32
    const float* W1  = (const float*)d_in[2];
    const float* b1  = (const float*)d_in[3];
    const float* Wc  = (const float*)d_in[4];
    const float* bc  = (const float*)d_in[5];
    float*       out = (float*)d_out;

    const int N   = in_sizes[0] / NFEAT;   // 50000
    const int E   = in_sizes[1] / 2;       // 1600000
    const int NP1 = N + 1;                 // +1 dummy row per slice

    char* ws = (char*)d_ws;
    size_t off = 0;
    float* hA    = (float*)(ws + off); off = align256(off + (size_t)NSLICE * NP1 * SFEAT * 4);
    float* hB    = (float*)(ws + off); off = align256(off + (size_t)NSLICE * NP1 * SFEAT * 4);
    int*   cnt   = (int*)  (ws + off); off = align256(off + (size_t)N * 4);
    float* dinv  = (float*)(ws + off); off = align256(off + (size_t)N * 4);
    int*   offs  = (int*)  (ws + off); off = align256(off + (size_t)(N + 1) * 4);
    int*   pos   = (int*)  (ws + off); off = align256(off + (size_t)N * 4);
    int*   esrc  = (int*)  (ws + off); off = align256(off + ((size_t)E + 64) * 4);

    hipMemsetAsync(cnt, 0, (size_t)N * 4, stream);

    deg_kernel<<<(E + 255) / 256, 256, 0, stream>>>(ei, cnt, E);
    dinv_kernel<<<(N + 255) / 256, 256, 0, stream>>>(cnt, dinv, N);
    scan_kernel<<<1, 256, 0, stream>>>(cnt, offs, pos, N);
    scatter_kernel<<<(E + 255) / 256, 256, 0, stream>>>(ei, pos, esrc, E);
    init_dummy_kernel<<<1, 256, 0, stream>>>(hA, hB, N, NP1);

    gemm1_kernel<<<(N + 63) / 64, 256, 0, stream>>>(x, W1, b1, dinv, hA, N, NP1);

    int ngrp = (N + 15) / 16;                     // 16 nodes per wave
    int hop_blocks = NSLICE * ((ngrp + 3) / 4);   // 4 waves per block
    for (int i = 0; i < CONV_TIME; ++i) {
        const float* gi = (i & 1) ? hB : hA;
        float*       go = (i & 1) ? hA : hB;
        hop_kernel<<<hop_blocks, 256, 0, stream>>>(gi, go, offs, esrc, dinv, N, NP1,
                                                   (i == CONV_TIME - 1) ? 1 : 0);
    }

    cls_kernel<<<(N + 255) / 256, 256, 0, stream>>>(hA, Wc, bc, out, N, NP1);
}

// Round 6
// 2657.662 us; speedup vs baseline: 2.7231x; 2.7231x over previous
//
#include <hip/hip_runtime.h>
#include <hip/hip_bf16.h>

#define NFEAT 256
#define NHID  128
#define NCLS  10
#define CONV_TIME 30
#define NSLICE 8          // feature slices == XCD count
#define SFEAT  16         // NHID / NSLICE; 64B rows

// ---------------------------------------------------------------- degree histogram
// NOTE: harness stages integer inputs as int32 (NOT int64) — read as int.
__global__ void deg_kernel(const int* __restrict__ ei, int* __restrict__ cnt, int E) {
    int e = blockIdx.x * blockDim.x + threadIdx.x;
    if (e < E) {
        int d = ei[(size_t)E + e];   // edge_index[1][e]
        atomicAdd(&cnt[d], 1);
    }
}

// ---------------------------------------------------------------- dinv = 1/sqrt(deg+1)
__global__ void dinv_kernel(const int* __restrict__ cnt, float* __restrict__ dinv, int n) {
    int i = blockIdx.x * blockDim.x + threadIdx.x;
    if (i < n) {
        float deg = (float)(cnt[i] + 1);   // +1 self loop; always >= 1
        dinv[i] = 1.0f / sqrtf(deg);
    }
}

// ---------------------------------------------------------------- exclusive scan (single block)
__global__ void scan_kernel(const int* __restrict__ cnt, int* __restrict__ offs,
                            int* __restrict__ pos, int n) {
    __shared__ int lds[256];
    int tid = threadIdx.x;
    int per = (n + 255) >> 8;
    int beg = tid * per;
    int end = min(beg + per, n);
    int sum = 0;
    for (int i = beg; i < end; ++i) sum += cnt[i];
    lds[tid] = sum;
    __syncthreads();
    if (tid == 0) {
        int acc = 0;
        for (int i = 0; i < 256; ++i) { int t = lds[i]; lds[i] = acc; acc += t; }
    }
    __syncthreads();
    int run = lds[tid];
    for (int i = beg; i < end; ++i) { offs[i] = run; pos[i] = run; run += cnt[i]; }
    if (tid == 255) offs[n] = run;
}

// ---------------------------------------------------------------- scatter edges into CSR (by dst)
// Payload: src id as ushort (N < 65536) — halves esrc stream + scatter writes.
__global__ void scatter_kernel(const int* __restrict__ ei, int* __restrict__ pos,
                               unsigned short* __restrict__ esrc, int E) {
    int e = blockIdx.x * blockDim.x + threadIdx.x;
    if (e < E) {
        int s = ei[e];
        int d = ei[(size_t)E + e];
        int p = atomicAdd(&pos[d], 1);
        esrc[p] = (unsigned short)s;
    }
}

// ---------------------------------------------------------------- zero the dummy row (row n) in both g buffers
__global__ void init_dummy_kernel(float* __restrict__ hA, float* __restrict__ hB,
                                  int n, int np1) {
    int t = threadIdx.x;
    if (t < NSLICE * SFEAT) {
        int sl = t >> 4, f = t & 15;
        size_t idx = (size_t)sl * np1 * SFEAT + (size_t)n * SFEAT + f;
        hA[idx] = 0.0f;
        hB[idx] = 0.0f;
    }
}

// ---------------------------------------------------------------- g0 = dinv * (x @ W1 + b1), sliced layout
__global__ __launch_bounds__(256) void gemm1_kernel(const float* __restrict__ x,
                                                    const float* __restrict__ W1,
                                                    const float* __restrict__ b1,
                                                    const float* __restrict__ dinv,
                                                    float* __restrict__ g, int M, int np1) {
    __shared__ float As[64][20];
    __shared__ float Bs[16][128];
    int tid = threadIdx.x;
    int m0  = blockIdx.x * 64;
    int tx  = tid & 15;
    int ty  = tid >> 4;
    int ar  = tid >> 2, aq = tid & 3;
    int br  = tid >> 4, bc = tid & 15;

    float acc[4][8];
#pragma unroll
    for (int i = 0; i < 4; ++i)
#pragma unroll
        for (int j = 0; j < 8; ++j) acc[i][j] = 0.0f;

    for (int kb = 0; kb < NFEAT; kb += 16) {
        float4 av = make_float4(0.f, 0.f, 0.f, 0.f);
        int arow = m0 + ar;
        if (arow < M) av = *(const float4*)(x + (size_t)arow * NFEAT + kb + aq * 4);
        *(float4*)&As[ar][aq * 4] = av;
        *(float4*)&Bs[br][bc * 8]     = *(const float4*)(W1 + (size_t)(kb + br) * NHID + bc * 8);
        *(float4*)&Bs[br][bc * 8 + 4] = *(const float4*)(W1 + (size_t)(kb + br) * NHID + bc * 8 + 4);
        __syncthreads();
#pragma unroll
        for (int k = 0; k < 16; ++k) {
            float a0 = As[ty * 4 + 0][k];
            float a1 = As[ty * 4 + 1][k];
            float a2 = As[ty * 4 + 2][k];
            float a3 = As[ty * 4 + 3][k];
            float4 b0 = *(float4*)&Bs[k][tx * 8];
            float4 b1v = *(float4*)&Bs[k][tx * 8 + 4];
            float bv[8] = {b0.x, b0.y, b0.z, b0.w, b1v.x, b1v.y, b1v.z, b1v.w};
            float avv[4] = {a0, a1, a2, a3};
#pragma unroll
            for (int i = 0; i < 4; ++i)
#pragma unroll
                for (int j = 0; j < 8; ++j)
                    acc[i][j] = fmaf(avv[i], bv[j], acc[i][j]);
        }
        __syncthreads();
    }
    int col0 = tx * 8;
    int sl   = col0 >> 4;
    int c0   = col0 & 15;
#pragma unroll
    for (int i = 0; i < 4; ++i) {
        int row = m0 + ty * 4 + i;
        if (row < M) {
            float dv = dinv[row];
            float* dst = g + (size_t)sl * np1 * SFEAT + (size_t)row * SFEAT + c0;
#pragma unroll
            for (int j = 0; j < 8; ++j)
                dst[j] = dv * (acc[i][j] + b1[col0 + j]);
        }
    }
}

// ---------------------------------------------------------------- one propagation hop (sliced, node-parallel slots)
// blockIdx & 7 = feature slice, round-robin onto the 8 XCDs -> each XCD's
// gathers stay inside its own 3.2MB slice (L2-resident; R4 proved FETCH 361->41MB).
// Wave = 16 node-slots x 4 lanes; lane holds float4 = quarter of the slot's
// 16-feat row. Each slot walks ITS OWN node's edge list: no cross-slot
// reduction. esrc is read as slot-uniform ushort loads (hardware broadcast
// across the 4 lanes; line stays L1-hot for its 32 in-line edges — NO
// nontemporal hint, that was R5's 218MB-FETCH regression). Unroll 8 keeps 8
// independent esrc->gather chains in flight. Degree divergence across slots
// handled by index clamp + select to dummy row n (zeroed, L1-hot).
__global__ __launch_bounds__(256) void hop_kernel(const float* __restrict__ gin,
                                                  float* __restrict__ gout,
                                                  const int* __restrict__ offs,
                                                  const unsigned short* __restrict__ esrc,
                                                  const float* __restrict__ dinv,
                                                  int n, int np1, int last) {
    int bid  = blockIdx.x;
    int sl   = bid & (NSLICE - 1);
    int grp  = (bid >> 3) * 4 + (threadIdx.x >> 6);   // 16-node group
    if (grp * 16 >= n) return;
    int lane = threadIdx.x & 63;
    int slot = lane >> 2;          // 0..15
    int fl   = lane & 3;           // float4 within the 16-feat slice
    int node = grp * 16 + slot;
    bool valid = node < n;
    int nodeC = valid ? node : n;
    const float4* __restrict__ gs4 = (const float4*)(gin + (size_t)sl * np1 * SFEAT);
    float4*       __restrict__ go4 = (float4*)(gout + (size_t)sl * np1 * SFEAT);

    int beg = 0, deg = 0;
    if (valid) { beg = offs[node]; deg = offs[node + 1] - beg; }
    int dmax = deg;
    dmax = max(dmax, __shfl_xor(dmax, 4, 64));
    dmax = max(dmax, __shfl_xor(dmax, 8, 64));
    dmax = max(dmax, __shfl_xor(dmax, 16, 64));
    dmax = max(dmax, __shfl_xor(dmax, 32, 64));

    float4 acc = make_float4(0.f, 0.f, 0.f, 0.f);
    int degm1 = (deg > 0) ? (deg - 1) : 0;
    for (int i = 0; i < dmax; i += 8) {
#pragma unroll
        for (int j = 0; j < 8; ++j) {
            int a   = beg + min(i + j, degm1);          // always in-bounds
            int src = (int)esrc[a];                     // slot-uniform 2B load
            src     = (i + j < deg) ? src : n;          // dummy row = zeros
            float4 v = gs4[(size_t)src * 4 + fl];
            acc.x += v.x; acc.y += v.y; acc.z += v.z; acc.w += v.w;
        }
    }
    float4 sf = gs4[(size_t)nodeC * 4 + fl];
    acc.x += sf.x; acc.y += sf.y; acc.z += sf.z; acc.w += sf.w;
    float dv = valid ? dinv[node] : 1.0f;
    float sc = last ? dv : dv * dv;
    acc.x *= sc; acc.y *= sc; acc.z *= sc; acc.w *= sc;
    if (valid) go4[(size_t)node * 4 + fl] = acc;
}

// ---------------------------------------------------------------- out = relu(h) @ Wc + bc (sliced h)
__global__ __launch_bounds__(256) void cls_kernel(const float* __restrict__ h,
                                                  const float* __restrict__ Wc,
                                                  const float* __restrict__ bc,
                                                  float* __restrict__ out, int n, int np1) {
    __shared__ float wc[NHID * NCLS];
    __shared__ float bcs[NCLS];
    int tid = threadIdx.x;
    for (int i = tid; i < NHID * NCLS; i += 256) wc[i] = Wc[i];
    if (tid < NCLS) bcs[tid] = bc[tid];
    __syncthreads();
    int i = blockIdx.x * 256 + tid;
    if (i >= n) return;
    float acc[NCLS];
#pragma unroll
    for (int c = 0; c < NCLS; ++c) acc[c] = bcs[c];
#pragma unroll
    for (int s = 0; s < NSLICE; ++s) {
        const float4* hr = (const float4*)(h + ((size_t)s * np1 + i) * SFEAT);
#pragma unroll
        for (int q = 0; q < 4; ++q) {
            float4 v = hr[q];
            float vs[4] = {fmaxf(v.x, 0.f), fmaxf(v.y, 0.f), fmaxf(v.z, 0.f), fmaxf(v.w, 0.f)};
#pragma unroll
            for (int j = 0; j < 4; ++j)
#pragma unroll
                for (int c = 0; c < NCLS; ++c)
                    acc[c] = fmaf(vs[j], wc[(s * SFEAT + q * 4 + j) * NCLS + c], acc[c]);
        }
    }
#pragma unroll
    for (int c = 0; c < NCLS; ++c) out[(size_t)i * NCLS + c] = acc[c];
}

// ----------------------------------------------------------------
static inline size_t align256(size_t x) { return (x + 255) & ~(size_t)255; }

extern "C" void kernel_launch(void* const* d_in, const int* in_sizes, int n_in,
                              void* d_out, int out_size, void* d_ws, size_t ws_size,
                              hipStream_t stream) {
    const float* x   = (const float*)d_in[0];
    const int*   ei  = (const int*)d_in[1];     // int64 in reference -> staged as int32
    const float* W1  = (const float*)d_in[2];
    const float* b1  = (const float*)d_in[3];
    const float* Wc  = (const float*)d_in[4];
    const float* bc  = (const float*)d_in[5];
    float*       out = (float*)d_out;

    const int N   = in_sizes[0] / NFEAT;   // 50000
    const int E   = in_sizes[1] / 2;       // 1600000
    const int NP1 = N + 1;                 // +1 dummy row per slice

    char* ws = (char*)d_ws;
    size_t off = 0;
    float*          hA   = (float*)(ws + off); off = align256(off + (size_t)NSLICE * NP1 * SFEAT * 4);
    float*          hB   = (float*)(ws + off); off = align256(off + (size_t)NSLICE * NP1 * SFEAT * 4);
    int*            cnt  = (int*)  (ws + off); off = align256(off + (size_t)N * 4);
    float*          dinv = (float*)(ws + off); off = align256(off + (size_t)N * 4);
    int*            offs = (int*)  (ws + off); off = align256(off + (size_t)(N + 1) * 4);
    int*            pos  = (int*)  (ws + off); off = align256(off + (size_t)N * 4);
    unsigned short* esrc = (unsigned short*)(ws + off); off = align256(off + ((size_t)E + 64) * 2);

    hipMemsetAsync(cnt, 0, (size_t)N * 4, stream);

    deg_kernel<<<(E + 255) / 256, 256, 0, stream>>>(ei, cnt, E);
    dinv_kernel<<<(N + 255) / 256, 256, 0, stream>>>(cnt, dinv, N);
    scan_kernel<<<1, 256, 0, stream>>>(cnt, offs, pos, N);
    scatter_kernel<<<(E + 255) / 256, 256, 0, stream>>>(ei, pos, esrc, E);
    init_dummy_kernel<<<1, 256, 0, stream>>>(hA, hB, N, NP1);

    gemm1_kernel<<<(N + 63) / 64, 256, 0, stream>>>(x, W1, b1, dinv, hA, N, NP1);

    int ngrp = (N + 15) / 16;                     // 16 nodes per wave
    int hop_blocks = NSLICE * ((ngrp + 3) / 4);   // 4 waves per block
    for (int i = 0; i < CONV_TIME; ++i) {
        const float* gi = (i & 1) ? hB : hA;
        float*       go = (i & 1) ? hA : hB;
        hop_kernel<<<hop_blocks, 256, 0, stream>>>(gi, go, offs, esrc, dinv, N, NP1,
                                                   (i == CONV_TIME - 1) ? 1 : 0);
    }

    cls_kernel<<<(N + 255) / 256, 256, 0, stream>>>(hA, Wc, bc, out, N, NP1);
}

// Round 7
// 2445.638 us; speedup vs baseline: 2.9591x; 1.0867x over previous
//
#include <hip/hip_runtime.h>
#include <hip/hip_bf16.h>

#define NFEAT 256
#define NHID  128
#define NCLS  10
#define CONV_TIME 30
#define NSLICE 8          // feature slices == XCD count
#define SFEAT  16         // NHID / NSLICE; 64B rows

// ---------------------------------------------------------------- degree histogram
// NOTE: harness stages integer inputs as int32 (NOT int64) — read as int.
__global__ void deg_kernel(const int* __restrict__ ei, int* __restrict__ cnt, int E) {
    int e = blockIdx.x * blockDim.x + threadIdx.x;
    if (e < E) {
        int d = ei[(size_t)E + e];   // edge_index[1][e]
        atomicAdd(&cnt[d], 1);
    }
}

// ---------------------------------------------------------------- dinv = 1/sqrt(deg+1)
__global__ void dinv_kernel(const int* __restrict__ cnt, float* __restrict__ dinv, int n) {
    int i = blockIdx.x * blockDim.x + threadIdx.x;
    if (i < n) {
        float deg = (float)(cnt[i] + 1);   // +1 self loop; always >= 1
        dinv[i] = 1.0f / sqrtf(deg);
    }
}

// ---------------------------------------------------------------- padded segment allocation
// Replaces the 123us serial scan. Each node gets a segment of round8(deg)
// entries; placement is arbitrary, so allocate via wave-aggregated atomicAdd:
// shfl prefix-sum of padded lengths within the wave, ONE global atomic per
// wave (784 total). pbeg/pos = segment start, plen = padded length.
__global__ void alloc_kernel(const int* __restrict__ cnt, int* __restrict__ alloc,
                             int* __restrict__ pbeg, int* __restrict__ plen,
                             int* __restrict__ pos, int n) {
    int i    = blockIdx.x * blockDim.x + threadIdx.x;
    int lane = threadIdx.x & 63;
    int pl   = 0;
    if (i < n) pl = (cnt[i] + 7) & ~7;
    int v = pl;
#pragma unroll
    for (int d = 1; d < 64; d <<= 1) {
        int t = __shfl_up(v, d, 64);
        if (lane >= d) v += t;
    }
    int total = __shfl(v, 63, 64);      // wave sum
    int excl  = v - pl;                 // exclusive prefix
    int base  = 0;
    if (lane == 63) base = atomicAdd(alloc, total);
    base = __shfl(base, 63, 64);
    if (i < n) {
        int seg = base + excl;
        pbeg[i] = seg;
        plen[i] = pl;
        pos[i]  = seg;
    }
}

// ---------------------------------------------------------------- pre-fill esrc with dummy id n
__global__ void fill_esrc_kernel(unsigned int* __restrict__ esrc32, unsigned int val, int nwords) {
    int i = blockIdx.x * blockDim.x + threadIdx.x;
    if (i < nwords) esrc32[i] = val;
}

// ---------------------------------------------------------------- scatter edges into CSR (by dst)
__global__ void scatter_kernel(const int* __restrict__ ei, int* __restrict__ pos,
                               unsigned short* __restrict__ esrc, int E) {
    int e = blockIdx.x * blockDim.x + threadIdx.x;
    if (e < E) {
        int s = ei[e];
        int d = ei[(size_t)E + e];
        int p = atomicAdd(&pos[d], 1);
        esrc[p] = (unsigned short)s;
    }
}

// ---------------------------------------------------------------- zero the dummy row (row n) in both g buffers
__global__ void init_dummy_kernel(float* __restrict__ hA, float* __restrict__ hB,
                                  int n, int np1) {
    int t = threadIdx.x;
    if (t < NSLICE * SFEAT) {
        int sl = t >> 4, f = t & 15;
        size_t idx = (size_t)sl * np1 * SFEAT + (size_t)n * SFEAT + f;
        hA[idx] = 0.0f;
        hB[idx] = 0.0f;
    }
}

// ---------------------------------------------------------------- g0 = dinv * (x @ W1 + b1), sliced layout
__global__ __launch_bounds__(256) void gemm1_kernel(const float* __restrict__ x,
                                                    const float* __restrict__ W1,
                                                    const float* __restrict__ b1,
                                                    const float* __restrict__ dinv,
                                                    float* __restrict__ g, int M, int np1) {
    __shared__ float As[64][20];
    __shared__ float Bs[16][128];
    int tid = threadIdx.x;
    int m0  = blockIdx.x * 64;
    int tx  = tid & 15;
    int ty  = tid >> 4;
    int ar  = tid >> 2, aq = tid & 3;
    int br  = tid >> 4, bc = tid & 15;

    float acc[4][8];
#pragma unroll
    for (int i = 0; i < 4; ++i)
#pragma unroll
        for (int j = 0; j < 8; ++j) acc[i][j] = 0.0f;

    for (int kb = 0; kb < NFEAT; kb += 16) {
        float4 av = make_float4(0.f, 0.f, 0.f, 0.f);
        int arow = m0 + ar;
        if (arow < M) av = *(const float4*)(x + (size_t)arow * NFEAT + kb + aq * 4);
        *(float4*)&As[ar][aq * 4] = av;
        *(float4*)&Bs[br][bc * 8]     = *(const float4*)(W1 + (size_t)(kb + br) * NHID + bc * 8);
        *(float4*)&Bs[br][bc * 8 + 4] = *(const float4*)(W1 + (size_t)(kb + br) * NHID + bc * 8 + 4);
        __syncthreads();
#pragma unroll
        for (int k = 0; k < 16; ++k) {
            float a0 = As[ty * 4 + 0][k];
            float a1 = As[ty * 4 + 1][k];
            float a2 = As[ty * 4 + 2][k];
            float a3 = As[ty * 4 + 3][k];
            float4 b0 = *(float4*)&Bs[k][tx * 8];
            float4 b1v = *(float4*)&Bs[k][tx * 8 + 4];
            float bv[8] = {b0.x, b0.y, b0.z, b0.w, b1v.x, b1v.y, b1v.z, b1v.w};
            float avv[4] = {a0, a1, a2, a3};
#pragma unroll
            for (int i = 0; i < 4; ++i)
#pragma unroll
                for (int j = 0; j < 8; ++j)
                    acc[i][j] = fmaf(avv[i], bv[j], acc[i][j]);
        }
        __syncthreads();
    }
    int col0 = tx * 8;
    int sl   = col0 >> 4;
    int c0   = col0 & 15;
#pragma unroll
    for (int i = 0; i < 4; ++i) {
        int row = m0 + ty * 4 + i;
        if (row < M) {
            float dv = dinv[row];
            float* dst = g + (size_t)sl * np1 * SFEAT + (size_t)row * SFEAT + c0;
#pragma unroll
            for (int j = 0; j < 8; ++j)
                dst[j] = dv * (acc[i][j] + b1[col0 + j]);
        }
    }
}

// ---------------------------------------------------------------- one propagation hop (sliced, node-parallel slots)
// blockIdx & 7 = feature slice, round-robin onto the 8 XCDs (R4: FETCH 361->41MB).
// Wave = 16 node-slots x 4 lanes; lane holds float4 of the slot's 16-feat row.
// Padded segments (multiple of 8) let each slot run a clean divergent loop over
// its OWN list: no wave-max, no per-edge clamp/select, finished slots are
// exec-masked (no wasted gathers — R6 burned ~29% of gathers on dummies).
// 8 edge ids per group come from ONE uint4 load (16B-aligned by construction).
__global__ __launch_bounds__(256) void hop_kernel(const float* __restrict__ gin,
                                                  float* __restrict__ gout,
                                                  const int* __restrict__ pbeg,
                                                  const int* __restrict__ plen,
                                                  const unsigned short* __restrict__ esrc,
                                                  const float* __restrict__ dinv,
                                                  int n, int np1, int last) {
    int bid  = blockIdx.x;
    int sl   = bid & (NSLICE - 1);
    int grp  = (bid >> 3) * 4 + (threadIdx.x >> 6);   // 16-node group
    if (grp * 16 >= n) return;
    int lane = threadIdx.x & 63;
    int slot = lane >> 2;          // 0..15
    int fl   = lane & 3;           // float4 within the 16-feat row
    int node = grp * 16 + slot;
    bool valid = node < n;
    int nodeC = valid ? node : n;
    const float4* __restrict__ gs4 = (const float4*)(gin + (size_t)sl * np1 * SFEAT);
    float4*       __restrict__ go4 = (float4*)(gout + (size_t)sl * np1 * SFEAT);

    int beg = 0, L = 0;
    if (valid) { beg = pbeg[node]; L = plen[node]; }

    float4 acc = make_float4(0.f, 0.f, 0.f, 0.f);
    const uint4* __restrict__ e4 = (const uint4*)esrc;
    for (int i = 0; i < L; i += 8) {
        uint4 w = e4[(beg + i) >> 3];          // 8 edge ids, slot-uniform
        int s0 = w.x & 0xFFFF, s1 = w.x >> 16;
        int s2 = w.y & 0xFFFF, s3 = w.y >> 16;
        int s4 = w.z & 0xFFFF, s5 = w.z >> 16;
        int s6 = w.w & 0xFFFF, s7 = w.w >> 16;
        float4 v0 = gs4[(size_t)s0 * 4 + fl];
        float4 v1 = gs4[(size_t)s1 * 4 + fl];
        float4 v2 = gs4[(size_t)s2 * 4 + fl];
        float4 v3 = gs4[(size_t)s3 * 4 + fl];
        float4 v4 = gs4[(size_t)s4 * 4 + fl];
        float4 v5 = gs4[(size_t)s5 * 4 + fl];
        float4 v6 = gs4[(size_t)s6 * 4 + fl];
        float4 v7 = gs4[(size_t)s7 * 4 + fl];
        acc.x += v0.x + v1.x + v2.x + v3.x + v4.x + v5.x + v6.x + v7.x;
        acc.y += v0.y + v1.y + v2.y + v3.y + v4.y + v5.y + v6.y + v7.y;
        acc.z += v0.z + v1.z + v2.z + v3.z + v4.z + v5.z + v6.z + v7.z;
        acc.w += v0.w + v1.w + v2.w + v3.w + v4.w + v5.w + v6.w + v7.w;
    }
    float4 sf = gs4[(size_t)nodeC * 4 + fl];
    acc.x += sf.x; acc.y += sf.y; acc.z += sf.z; acc.w += sf.w;
    float dv = valid ? dinv[node] : 1.0f;
    float sc = last ? dv : dv * dv;
    acc.x *= sc; acc.y *= sc; acc.z *= sc; acc.w *= sc;
    if (valid) go4[(size_t)node * 4 + fl] = acc;
}

// ---------------------------------------------------------------- out = relu(h) @ Wc + bc (sliced h)
__global__ __launch_bounds__(256) void cls_kernel(const float* __restrict__ h,
                                                  const float* __restrict__ Wc,
                                                  const float* __restrict__ bc,
                                                  float* __restrict__ out, int n, int np1) {
    __shared__ float wc[NHID * NCLS];
    __shared__ float bcs[NCLS];
    int tid = threadIdx.x;
    for (int i = tid; i < NHID * NCLS; i += 256) wc[i] = Wc[i];
    if (tid < NCLS) bcs[tid] = bc[tid];
    __syncthreads();
    int i = blockIdx.x * 256 + tid;
    if (i >= n) return;
    float acc[NCLS];
#pragma unroll
    for (int c = 0; c < NCLS; ++c) acc[c] = bcs[c];
#pragma unroll
    for (int s = 0; s < NSLICE; ++s) {
        const float4* hr = (const float4*)(h + ((size_t)s * np1 + i) * SFEAT);
#pragma unroll
        for (int q = 0; q < 4; ++q) {
            float4 v = hr[q];
            float vs[4] = {fmaxf(v.x, 0.f), fmaxf(v.y, 0.f), fmaxf(v.z, 0.f), fmaxf(v.w, 0.f)};
#pragma unroll
            for (int j = 0; j < 4; ++j)
#pragma unroll
                for (int c = 0; c < NCLS; ++c)
                    acc[c] = fmaf(vs[j], wc[(s * SFEAT + q * 4 + j) * NCLS + c], acc[c]);
        }
    }
#pragma unroll
    for (int c = 0; c < NCLS; ++c) out[(size_t)i * NCLS + c] = acc[c];
}

// ----------------------------------------------------------------
static inline size_t align256(size_t x) { return (x + 255) & ~(size_t)255; }

extern "C" void kernel_launch(void* const* d_in, const int* in_sizes, int n_in,
                              void* d_out, int out_size, void* d_ws, size_t ws_size,
                              hipStream_t stream) {
    const float* x   = (const float*)d_in[0];
    const int*   ei  = (const int*)d_in[1];     // int64 in reference -> staged as int32
    const float* W1  = (const float*)d_in[2];
    const float* b1  = (const float*)d_in[3];
    const float* Wc  = (const float*)d_in[4];
    const float* bc  = (const float*)d_in[5];
    float*       out = (float*)d_out;

    const int N    = in_sizes[0] / NFEAT;   // 50000
    const int E    = in_sizes[1] / 2;       // 1600000
    const int NP1  = N + 1;                 // +1 dummy row per slice
    const int EPAD = E + 8 * N + 64;        // worst-case padded CSR size

    char* ws = (char*)d_ws;
    size_t off = 0;
    float*          hA   = (float*)(ws + off); off = align256(off + (size_t)NSLICE * NP1 * SFEAT * 4);
    float*          hB   = (float*)(ws + off); off = align256(off + (size_t)NSLICE * NP1 * SFEAT * 4);
    int*            cnt  = (int*)  (ws + off); off = align256(off + (size_t)(N + 64) * 4);  // +alloc counter
    float*          dinv = (float*)(ws + off); off = align256(off + (size_t)N * 4);
    int*            pbeg = (int*)  (ws + off); off = align256(off + (size_t)N * 4);
    int*            plen = (int*)  (ws + off); off = align256(off + (size_t)N * 4);
    int*            pos  = (int*)  (ws + off); off = align256(off + (size_t)N * 4);
    unsigned short* esrc = (unsigned short*)(ws + off); off = align256(off + (size_t)EPAD * 2);
    int*            alloc = cnt + N;        // covered by the cnt memset

    hipMemsetAsync(cnt, 0, (size_t)(N + 64) * 4, stream);

    deg_kernel<<<(E + 255) / 256, 256, 0, stream>>>(ei, cnt, E);
    dinv_kernel<<<(N + 255) / 256, 256, 0, stream>>>(cnt, dinv, N);
    alloc_kernel<<<(N + 255) / 256, 256, 0, stream>>>(cnt, alloc, pbeg, plen, pos, N);
    {
        unsigned int v = ((unsigned)N << 16) | (unsigned)N;
        int nwords = EPAD / 2;
        fill_esrc_kernel<<<(nwords + 255) / 256, 256, 0, stream>>>((unsigned int*)esrc, v, nwords);
    }
    scatter_kernel<<<(E + 255) / 256, 256, 0, stream>>>(ei, pos, esrc, E);
    init_dummy_kernel<<<1, 256, 0, stream>>>(hA, hB, N, NP1);

    gemm1_kernel<<<(N + 63) / 64, 256, 0, stream>>>(x, W1, b1, dinv, hA, N, NP1);

    int ngrp = (N + 15) / 16;                     // 16 nodes per wave
    int hop_blocks = NSLICE * ((ngrp + 3) / 4);   // 4 waves per block
    for (int i = 0; i < CONV_TIME; ++i) {
        const float* gi = (i & 1) ? hB : hA;
        float*       go = (i & 1) ? hA : hB;
        hop_kernel<<<hop_blocks, 256, 0, stream>>>(gi, go, pbeg, plen, esrc, dinv, N, NP1,
                                                   (i == CONV_TIME - 1) ? 1 : 0);
    }

    cls_kernel<<<(N + 255) / 256, 256, 0, stream>>>(hA, Wc, bc, out, N, NP1);
}